// Round 5
// baseline (377.810 us; speedup 1.0000x reference)
//
#include <hip/hip_runtime.h>
#include <hip/hip_bf16.h>
#include <hip/hip_fp16.h>
#include <math.h>

#define NL 4
#define Dm 512
#define FFD 1024
#define Bb 8
#define Ss 480
#define TPT 15
#define ROWS (Bb*Ss)   // 3840

typedef __attribute__((ext_vector_type(8))) short short8v;
typedef __attribute__((ext_vector_type(4))) float f32x4;
typedef __attribute__((ext_vector_type(2))) _Float16 half2v;
typedef __attribute__((ext_vector_type(8))) _Float16 half8v;

#if __has_builtin(__builtin_amdgcn_fdot2)
#define FDOT2(a, b, c) __builtin_amdgcn_fdot2(a, b, c, false)
#else
#define FDOT2(a, b, c) ((c) + (float)(a)[0] * (float)(b)[0] + (float)(a)[1] * (float)(b)[1])
#endif

// global -> LDS direct (16B/lane). lbase wave-uniform; HW dest = lbase + lane*16.
__device__ __forceinline__ void gld_lds16(const void* g, void* lbase) {
#if __has_builtin(__builtin_amdgcn_global_load_lds)
    __builtin_amdgcn_global_load_lds((const __attribute__((address_space(1))) void*)g,
                                     (__attribute__((address_space(3))) void*)lbase, 16, 0, 0);
#else
    (void)g; (void)lbase;
#endif
}

// ---------------- row stats of x (layer-0 LN1): one wave per row ----------------
__global__ __launch_bounds__(256) void stats0_kernel(const float* __restrict__ x,
                                                     float* __restrict__ st) {
    int w = threadIdx.x >> 6, lane = threadIdx.x & 63;
    int row = blockIdx.x * 4 + w;
    const float* xr = x + (size_t)row * Dm + lane * 8;
    float4 v0 = *(const float4*)xr;
    float4 v1 = *(const float4*)(xr + 4);
    float v[8] = { v0.x, v0.y, v0.z, v0.w, v1.x, v1.y, v1.z, v1.w };
    float s = 0.0f, q = 0.0f;
#pragma unroll
    for (int e = 0; e < 8; e++) { s += v[e]; q += v[e] * v[e]; }
#pragma unroll
    for (int off = 1; off < 64; off <<= 1) { s += __shfl_xor(s, off); q += __shfl_xor(q, off); }
    if (lane == 0) { st[row * 2] = s; st[row * 2 + 1] = q; }
}

// -------- merged weight transpose+convert: all 4 weight types, all layers -------
__global__ __launch_bounds__(256) void conv_all(const float* __restrict__ Wqkv,
                                                const float* __restrict__ Wo,
                                                const float* __restrict__ W1,
                                                const float* __restrict__ W2,
                                                __hip_bfloat16* __restrict__ oq,
                                                __hip_bfloat16* __restrict__ oo,
                                                __hip_bfloat16* __restrict__ o1,
                                                __hip_bfloat16* __restrict__ o2) {
    int type = blockIdx.z >> 2, l = blockIdx.z & 3;
    int K, N; const float* src; __hip_bfloat16* dst;
    if (type == 0)      { K = 512;  N = 1536; src = Wqkv; dst = oq; }
    else if (type == 1) { K = 512;  N = 512;  src = Wo;   dst = oo; }
    else if (type == 2) { K = 512;  N = 1024; src = W1;   dst = o1; }
    else                { K = 1024; N = 512;  src = W2;   dst = o2; }
    int n0 = blockIdx.x * 32, k0 = blockIdx.y * 32;
    if (n0 >= N || k0 >= K) return;
    src += (size_t)l * K * N;
    dst += (size_t)l * K * N;

    __shared__ float t[32][33];
    int tx = threadIdx.x & 31, ty = threadIdx.x >> 5;
#pragma unroll
    for (int r = 0; r < 4; r++)
        t[ty * 4 + r][tx] = src[(size_t)(k0 + ty * 4 + r) * N + n0 + tx];
    __syncthreads();
#pragma unroll
    for (int r = 0; r < 4; r++)
        dst[(size_t)(n0 + ty * 4 + r) * K + k0 + tx] = __float2bfloat16(t[tx][ty * 4 + r]);
}

// ---- bf16 MFMA GEMM, BMxBN tile, BK=64, 4 waves, 2-phase double-buffered -------
// LNA=1: A is fp32 + per-row {sum,sumsq} stats; LN applied during reg-staging.
// EMIT=1: epilogue emits per-row {sum,sumsq} of C into stOut (atomicAdd).
// OUTMODE: 0 f32, 1 bf16, 2 f16.  ACT: 1 = exact GELU.
template <int BM, int BN, int ACT, int RES, int OUTMODE, int LNA, int EMIT>
__global__ __launch_bounds__(256) void gemm_mfma(const void* __restrict__ Ain,
                                                 const __hip_bfloat16* __restrict__ Bt,
                                                 const float* __restrict__ bias,
                                                 const float* __restrict__ res,
                                                 void* __restrict__ C,
                                                 const float* __restrict__ stIn,
                                                 float* __restrict__ stOut,
                                                 const float* __restrict__ lng,
                                                 const float* __restrict__ lnb,
                                                 int M, int N, int K) {
    constexpr int MF = BM / 32;            // m-frags per wave
    constexpr int NF = BN / 32;            // n-frags per wave
    constexpr int ACc = BM / 32;           // A 256-chunk groups
    constexpr int BCc = BN / 32;           // B 256-chunk groups
    __shared__ __align__(16) short As[2][BM * 64];
    __shared__ __align__(16) short Bs[2][BN * 64];
    const int bm = blockIdx.y * BM, bn = blockIdx.x * BN;
    const int tid = threadIdx.x;
    const int w = tid >> 6, lane = tid & 63;
    const int wm = (w >> 1) * (BM / 2), wn = (w & 1) * (BN / 2);
    const int l16 = lane & 15, lq = lane >> 4;
    const short* Ag = (const short*)Ain;
    const float* Af = (const float*)Ain;
    const short* Bg = (const short*)Bt;
    const int nt = K >> 6;

    f32x4 acc[MF][NF] = {};

    // ---- hoisted per-thread A-chunk geometry (+ LN stats if LNA) ----
    int rowA[ACc], csA[ACc];
    float meanA[ACc], rstdA[ACc];
#pragma unroll
    for (int c = 0; c < ACc; c++) {
        int e = c * 256 + tid;
        rowA[c] = e >> 3;
        csA[c] = ((e & 7) ^ (rowA[c] & 7)) * 8;        // source element offset
        if (LNA) {
            float s = stIn[(bm + rowA[c]) * 2], q = stIn[(bm + rowA[c]) * 2 + 1];
            float mu = s * (1.0f / Dm);
            meanA[c] = mu;
            rstdA[c] = rsqrtf(q * (1.0f / Dm) - mu * mu + 1e-5f);
        }
    }

    float4 a0[ACc], a1[ACc], g0[ACc], g1[ACc], b0[ACc], b1[ACc];
    auto loadA = [&](int t) {                          // issue-early (T14)
#pragma unroll
        for (int c = 0; c < ACc; c++) {
            const float* src = Af + (size_t)(bm + rowA[c]) * K + t * 64 + csA[c];
            a0[c] = *(const float4*)src;
            a1[c] = *(const float4*)(src + 4);
            g0[c] = *(const float4*)(lng + t * 64 + csA[c]);
            g1[c] = *(const float4*)(lng + t * 64 + csA[c] + 4);
            b0[c] = *(const float4*)(lnb + t * 64 + csA[c]);
            b1[c] = *(const float4*)(lnb + t * 64 + csA[c] + 4);
        }
    };
    auto writeA = [&](int buf) {                       // write-late
#pragma unroll
        for (int c = 0; c < ACc; c++) {
            float av[8] = { a0[c].x, a0[c].y, a0[c].z, a0[c].w, a1[c].x, a1[c].y, a1[c].z, a1[c].w };
            float gv[8] = { g0[c].x, g0[c].y, g0[c].z, g0[c].w, g1[c].x, g1[c].y, g1[c].z, g1[c].w };
            float bv[8] = { b0[c].x, b0[c].y, b0[c].z, b0[c].w, b1[c].x, b1[c].y, b1[c].z, b1[c].w };
            short8v pk;
#pragma unroll
            for (int e = 0; e < 8; e++) {
                __hip_bfloat16 t16 = __float2bfloat16((av[e] - meanA[c]) * rstdA[c] * gv[e] + bv[e]);
                pk[e] = __builtin_bit_cast(short, t16);
            }
            *(short8v*)&As[buf][(c * 256 + tid) * 8] = pk;
        }
    };
    auto stageA = [&](int t, int buf) {                // bf16 direct DMA path
#pragma unroll
        for (int c = 0; c < ACc; c++)
            gld_lds16(Ag + (size_t)(bm + rowA[c]) * K + t * 64 + csA[c],
                      &As[buf][(c * 256 + w * 64) * 8]);
    };
    auto stageB = [&](int t, int buf) {
#pragma unroll
        for (int c = 0; c < BCc; c++) {
            int e = c * 256 + tid;
            int row = e >> 3;
            int cs = ((e & 7) ^ (row & 7)) * 8;
            gld_lds16(Bg + (size_t)(bn + row) * K + t * 64 + cs,
                      &Bs[buf][(c * 256 + w * 64) * 8]);
        }
    };

    if (LNA) loadA(0); else stageA(0, 0);
    stageB(0, 0);
    if (LNA) writeA(0);
    __syncthreads();
    int cur = 0;
    for (int t = 0; t < nt; ++t) {
        bool pf = (t + 1 < nt);
        if (pf) {
            if (LNA) loadA(t + 1); else stageA(t + 1, cur ^ 1);
            stageB(t + 1, cur ^ 1);
        }
#pragma unroll
        for (int kc = 0; kc < 2; ++kc) {
            short8v af[MF], bf[NF];
#pragma unroll
            for (int i = 0; i < MF; i++) {
                int row = wm + i * 16 + l16;
                int ch = (kc * 4 + lq) ^ (row & 7);
                af[i] = *(const short8v*)(&As[cur][row * 64 + ch * 8]);
            }
#pragma unroll
            for (int j = 0; j < NF; j++) {
                int col = wn + j * 16 + l16;
                int ch2 = (kc * 4 + lq) ^ (col & 7);
                bf[j] = *(const short8v*)(&Bs[cur][col * 64 + ch2 * 8]);
            }
#pragma unroll
            for (int i = 0; i < MF; i++)
#pragma unroll
                for (int j = 0; j < NF; j++)
                    acc[i][j] = __builtin_amdgcn_mfma_f32_16x16x32_bf16(
                        af[i], bf[j], acc[i][j], 0, 0, 0);
        }
        if (pf && LNA) writeA(cur ^ 1);    // waits A loads; MFMA above hid latency
        __syncthreads();
        cur ^= 1;
    }

    float vsum[MF][4], vsq[MF][4];
    if (EMIT) {
#pragma unroll
        for (int i = 0; i < MF; i++)
#pragma unroll
            for (int r = 0; r < 4; r++) { vsum[i][r] = 0.0f; vsq[i][r] = 0.0f; }
    }
#pragma unroll
    for (int i = 0; i < MF; i++) {
#pragma unroll
        for (int j = 0; j < NF; j++) {
#pragma unroll
            for (int r = 0; r < 4; r++) {
                int mrow = bm + wm + i * 16 + lq * 4 + r;
                int ncol = bn + wn + j * 16 + l16;
                float v = acc[i][j][r] + bias[ncol];
                if (ACT == 1) v = 0.5f * v * (1.0f + erff(v * 0.70710678118f));
                if (RES) v += res[(size_t)mrow * N + ncol];
                if (OUTMODE == 0)      ((float*)C)[(size_t)mrow * N + ncol] = v;
                else if (OUTMODE == 1) ((__hip_bfloat16*)C)[(size_t)mrow * N + ncol] = __float2bfloat16(v);
                else                   ((__half*)C)[(size_t)mrow * N + ncol] = __float2half(v);
                if (EMIT) { vsum[i][r] += v; vsq[i][r] += v * v; }
            }
        }
    }
    if (EMIT) {
#pragma unroll
        for (int i = 0; i < MF; i++)
#pragma unroll
            for (int r = 0; r < 4; r++) {
                float s = vsum[i][r], q = vsq[i][r];
#pragma unroll
                for (int off = 1; off < 16; off <<= 1) {
                    s += __shfl_xor(s, off);
                    q += __shfl_xor(q, off);
                }
                if (l16 == 0) {
                    int row = bm + wm + i * 16 + lq * 4 + r;
                    atomicAdd(&stOut[row * 2], s);
                    atomicAdd(&stOut[row * 2 + 1], q);
                }
            }
    }
}

// ------------- Attention: 1 wave per (b,q), all 8 heads, f16 fdot2 --------------
__global__ __launch_bounds__(256) void attn_sparse(const _Float16* __restrict__ qkv,
                                                   const int* __restrict__ ids,
                                                   const int* __restrict__ npf_p,
                                                   __hip_bfloat16* __restrict__ outb) {
    __shared__ _Float16 qs[4][512];
    __shared__ float ps[4][8][24];
    int w = threadIdx.x >> 6, lane = threadIdx.x & 63;
    int bq = blockIdx.x * 4 + w;
    int q = bq % Ss, b = bq / Ss;
    int npf = npf_p[0];
    int qt = q / TPT;
    int qid = ids[bq];

    *(half8v*)&qs[w][lane * 8] = *(const half8v*)&qkv[(size_t)bq * 1536 + lane * 8];
    __syncthreads();

    int h = lane >> 3, cp = lane & 7;

    half2v qreg[32];
#pragma unroll
    for (int i = 0; i < 32; i++) qreg[i] = *(const half2v*)&qs[w][h * 64 + i * 2];

    float s[3];
#pragma unroll
    for (int i = 0; i < 3; i++) {
        int c = cp + i * 8;
        float sv = -INFINITY;
        if (c < 23) {
            bool ok; int k;
            if (c < 15) { k = qt * TPT + c; ok = true; }
            else { int dt = c - 14; int kt = qt - dt; k = kt * TPT; ok = (kt >= 0) && (dt <= npf); }
            if (ok && ids[b * Ss + k] == qid) {
                const half8v* kr = (const half8v*)&qkv[(size_t)(b * Ss + k) * 1536 + 512 + h * 64];
                float dot = 0.0f;
#pragma unroll
                for (int cch = 0; cch < 8; cch++) {
                    half8v kv = kr[cch];
#pragma unroll
                    for (int e = 0; e < 4; e++) {
                        half2v kk = { kv[e * 2], kv[e * 2 + 1] };
                        dot = FDOT2(qreg[cch * 4 + e], kk, dot);
                    }
                }
                sv = 6.0f * tanhf(dot * (0.125f / 6.0f));
            }
        }
        s[i] = sv;
    }

    float m = fmaxf(fmaxf(s[0], s[1]), s[2]);
    for (int off = 1; off < 8; off <<= 1) m = fmaxf(m, __shfl_xor(m, off));
    float p0 = expf(s[0] - m), p1 = expf(s[1] - m), p2 = expf(s[2] - m);
    float l = p0 + p1 + p2;
    for (int off = 1; off < 8; off <<= 1) l += __shfl_xor(l, off);
    float inv = 1.0f / l;
    if (cp < 8)       ps[w][h][cp]      = p0 * inv;
    if (cp + 8 < 23)  ps[w][h][cp + 8]  = p1 * inv;
    if (cp + 16 < 23) ps[w][h][cp + 16] = p2 * inv;
    __syncthreads();

    int dg = lane & 7;
    float o[8] = {};
    for (int c = 0; c < 23; c++) {
        float p = ps[w][h][c];
        if (p != 0.0f) {
            int k = (c < 15) ? (qt * TPT + c) : ((qt - (c - 14)) * TPT);
            half8v vv = *(const half8v*)&qkv[(size_t)(b * Ss + k) * 1536 + 1024 + h * 64 + dg * 8];
#pragma unroll
            for (int e = 0; e < 8; e++) o[e] += p * (float)vv[e];
        }
    }
    short8v pack;
#pragma unroll
    for (int e = 0; e < 8; e++) {
        __hip_bfloat16 t = __float2bfloat16(o[e]);
        pack[e] = __builtin_bit_cast(short, t);
    }
    *(short8v*)&outb[(size_t)bq * Dm + h * 64 + dg * 8] = pack;
}

extern "C" void kernel_launch(void* const* d_in, const int* in_sizes, int n_in,
                              void* d_out, int out_size, void* d_ws, size_t ws_size,
                              hipStream_t stream) {
    const float* x    = (const float*)d_in[0];
    const int*   ids  = (const int*)d_in[1];
    const int*   npf  = (const int*)d_in[2];
    const float* Wqkv = (const float*)d_in[3];
    const float* bqkv = (const float*)d_in[4];
    const float* Wo   = (const float*)d_in[5];
    const float* bo   = (const float*)d_in[6];
    const float* g1   = (const float*)d_in[7];
    const float* b1   = (const float*)d_in[8];
    const float* g2   = (const float*)d_in[9];
    const float* b2   = (const float*)d_in[10];
    const float* W1   = (const float*)d_in[11];
    const float* bf1  = (const float*)d_in[12];
    const float* W2   = (const float*)d_in[13];
    const float* bf2  = (const float*)d_in[14];
    float* out = (float*)d_out;

    char* p = (char*)d_ws;
    float*          stats = (float*)p;            p += (size_t)9 * ROWS * 2 * 4;
    _Float16*       qkvb  = (_Float16*)p;         p += (size_t)ROWS * 3 * Dm * 2;
    __hip_bfloat16* attnb = (__hip_bfloat16*)p;   p += (size_t)ROWS * Dm * 2;
    __hip_bfloat16* fb    = (__hip_bfloat16*)p;   p += (size_t)ROWS * FFD * 2;
    __hip_bfloat16* Wqkv_t= (__hip_bfloat16*)p;   p += (size_t)NL * Dm * 3 * Dm * 2;
    __hip_bfloat16* Wo_t  = (__hip_bfloat16*)p;   p += (size_t)NL * Dm * Dm * 2;
    __hip_bfloat16* W1_t  = (__hip_bfloat16*)p;   p += (size_t)NL * Dm * FFD * 2;
    __hip_bfloat16* W2_t  = (__hip_bfloat16*)p;   p += (size_t)NL * FFD * Dm * 2;

    hipMemsetAsync(stats, 0, (size_t)9 * ROWS * 2 * 4, stream);
    conv_all<<<dim3(48, 32, 16), 256, 0, stream>>>(Wqkv, Wo, W1, W2,
                                                   Wqkv_t, Wo_t, W1_t, W2_t);
    stats0_kernel<<<ROWS / 4, 256, 0, stream>>>(x, stats);

    for (int l = 0; l < NL; l++) {
        const float* xin = (l == 0) ? x : out;
        float* st_ln1 = stats + (size_t)(2 * l) * ROWS * 2;
        float* st_ln2 = stats + (size_t)(2 * l + 1) * ROWS * 2;
        float* st_nx  = stats + (size_t)(2 * l + 2) * ROWS * 2;

        // LN1 + QKV GEMM (A = fp32 xin, LN applied in staging), out f16
        gemm_mfma<64, 128, 0, 0, 2, 1, 0><<<dim3(12, 60), 256, 0, stream>>>(
            xin, Wqkv_t + (size_t)l * Dm * 3 * Dm, bqkv + l * 3 * Dm, nullptr, qkvb,
            st_ln1, nullptr, g1 + l * Dm, b1 + l * Dm, ROWS, 3 * Dm, Dm);
        attn_sparse<<<ROWS / 4, 256, 0, stream>>>(qkvb, ids, npf, attnb);
        // Wo GEMM + residual -> out fp32, emits LN2 stats
        gemm_mfma<64, 64, 0, 1, 0, 0, 1><<<dim3(8, 60), 256, 0, stream>>>(
            attnb, Wo_t + (size_t)l * Dm * Dm, bo + l * Dm, xin, out,
            nullptr, st_ln2, nullptr, nullptr, ROWS, Dm, Dm);
        // LN2 + FF1 GEMM + GELU -> fb bf16
        gemm_mfma<64, 128, 1, 0, 1, 1, 0><<<dim3(8, 60), 256, 0, stream>>>(
            out, W1_t + (size_t)l * Dm * FFD, bf1 + l * FFD, nullptr, fb,
            st_ln2, nullptr, g2 + l * Dm, b2 + l * Dm, ROWS, FFD, Dm);
        // FF2 GEMM + residual -> out fp32 (in-place), emits next-layer LN1 stats
        gemm_mfma<64, 64, 0, 1, 0, 0, 1><<<dim3(8, 60), 256, 0, stream>>>(
            fb, W2_t + (size_t)l * FFD * Dm, bf2 + l * Dm, out, out,
            nullptr, st_nx, nullptr, nullptr, ROWS, Dm, FFD);
    }
}